// Round 3
// baseline (256.775 us; speedup 1.0000x reference)
//
#include <hip/hip_runtime.h>
#include <hip/hip_fp16.h>
#include <math.h>

// Problem constants (fixed by reference setup_inputs)
#define E_ 4
#define L_ 10
#define S_ 1024
#define F_ 256
#define T_ 1024
#define NROW (E_*L_*S_)     // 40960 rows of the input GEMM
#define NH   48             // Fourier harmonics (cos+sin each); tail e^-11.1
#define CSW  224            // padded CS/BT row width in halves (194 live + pad)

// workspace layout (float indices). OUT aliases MT (MT dead after kF).
#define OFF_M   32768                          // fp32 MT[el][f][s] (= OUT alias)
#define OFF_CS  (32768 + (size_t)NROW * F_)    // f16 CS[el][f][CSW] hi/lo pairs
#define OFF_BT  (OFF_CS + (size_t)40 * F_ * CSW / 2)   // f16 BT[t][CSW]
#define OFF_PT  (OFF_BT + (size_t)T_ * CSW / 2)        // f16 PT[256][256]

typedef _Float16 half8 __attribute__((ext_vector_type(8)));
typedef float f32x4v __attribute__((ext_vector_type(4)));
typedef float f32x2 __attribute__((ext_vector_type(2)));

__device__ __forceinline__ unsigned int encf(float x) {
  unsigned int b = __float_as_uint(x);
  return (b & 0x80000000u) ? ~b : (b | 0x80000000u);
}
__device__ __forceinline__ float decf(unsigned int u) {
  unsigned int b = (u & 0x80000000u) ? (u ^ 0x80000000u) : ~u;
  return __uint_as_float(b);
}
__device__ __forceinline__ void put_hl(_Float16* p, float v) {
  _Float16 h = (_Float16)v;
  _Float16 l = (_Float16)(v - (float)h);
  p[0] = h; p[1] = l;
}

// K_pt: PT[c][k] = (f16)P[k][c].
__global__ __launch_bounds__(256) void k_pt(const float* __restrict__ P,
                                            _Float16* __restrict__ PT) {
  const int k = blockIdx.x;
  const int c = threadIdx.x;
  PT[(size_t)c * F_ + k] = (_Float16)P[(size_t)k * F_ + c];
}

// K0: m = matrix @ params via MFMA f16 hi/lo split; writes M TRANSPOSED:
// MT[el][f][s]. Fused global min/max.
// R2: ZERO-LDS / ZERO-BARRIER. MFMA fragments are 16B-contiguous in global
// memory for both operands, so each wave direct-loads its fragments
// (A: 2xfloat4 -> f16 hi/lo in-register; B: half8), 1-chunk register
// prefetch. A re-reads across the block's 4 waves hit L1/L2; PT is
// L2-resident. No __syncthreads anywhere -> waves slip freely (TLP).
__global__ __launch_bounds__(256) void k0_mfma(const float* __restrict__ A,
                                               const _Float16* __restrict__ PT,
                                               float* __restrict__ MT,
                                               unsigned int* __restrict__ slots) {
  const int tid = threadIdx.x;
  const int wave = tid >> 6, lane = tid & 63;
  const int nn = lane & 15, quad = lane >> 4;
  const int row0 = blockIdx.x * 64;
  const int el = blockIdx.x >> 4;
  const int s0 = (blockIdx.x & 15) * 64;

  const float* ap0 = A + (size_t)(row0 + 0 * 16 + nn) * F_ + quad * 8;
  const float* ap1 = A + (size_t)(row0 + 1 * 16 + nn) * F_ + quad * 8;
  const float* ap2 = A + (size_t)(row0 + 2 * 16 + nn) * F_ + quad * 8;
  const float* ap3 = A + (size_t)(row0 + 3 * 16 + nn) * F_ + quad * 8;
  const _Float16* bp0 = PT + (size_t)(wave * 64 + 0 * 16 + nn) * F_ + quad * 8;
  const _Float16* bp1 = PT + (size_t)(wave * 64 + 1 * 16 + nn) * F_ + quad * 8;
  const _Float16* bp2 = PT + (size_t)(wave * 64 + 2 * 16 + nn) * F_ + quad * 8;
  const _Float16* bp3 = PT + (size_t)(wave * 64 + 3 * 16 + nn) * F_ + quad * 8;

  f32x4v acc[4][4];
#pragma unroll
  for (int rt = 0; rt < 4; ++rt)
#pragma unroll
    for (int ct = 0; ct < 4; ++ct) acc[rt][ct] = (f32x4v){0.f, 0.f, 0.f, 0.f};

  // prefetch chunk 0 (raw)
  float4 pa[4][2];
  half8 pb[4];
  pa[0][0] = ((const float4*)ap0)[0]; pa[0][1] = ((const float4*)ap0)[1];
  pa[1][0] = ((const float4*)ap1)[0]; pa[1][1] = ((const float4*)ap1)[1];
  pa[2][0] = ((const float4*)ap2)[0]; pa[2][1] = ((const float4*)ap2)[1];
  pa[3][0] = ((const float4*)ap3)[0]; pa[3][1] = ((const float4*)ap3)[1];
  pb[0] = *(const half8*)bp0; pb[1] = *(const half8*)bp1;
  pb[2] = *(const half8*)bp2; pb[3] = *(const half8*)bp3;

#pragma unroll
  for (int kc = 0; kc < 8; ++kc) {
    // snapshot current chunk into consume regs
    float4 ca[4][2];
    half8 bf[4];
#pragma unroll
    for (int rt = 0; rt < 4; ++rt) { ca[rt][0] = pa[rt][0]; ca[rt][1] = pa[rt][1]; }
#pragma unroll
    for (int ct = 0; ct < 4; ++ct) bf[ct] = pb[ct];
    // issue next chunk's loads (in flight across convert + 32 MFMAs)
    if (kc < 7) {
      const int o = (kc + 1) * 32;
      pa[0][0] = ((const float4*)(ap0 + o))[0]; pa[0][1] = ((const float4*)(ap0 + o))[1];
      pa[1][0] = ((const float4*)(ap1 + o))[0]; pa[1][1] = ((const float4*)(ap1 + o))[1];
      pa[2][0] = ((const float4*)(ap2 + o))[0]; pa[2][1] = ((const float4*)(ap2 + o))[1];
      pa[3][0] = ((const float4*)(ap3 + o))[0]; pa[3][1] = ((const float4*)(ap3 + o))[1];
      pb[0] = *(const half8*)(bp0 + o); pb[1] = *(const half8*)(bp1 + o);
      pb[2] = *(const half8*)(bp2 + o); pb[3] = *(const half8*)(bp3 + o);
    }
    // convert + MFMA, per rt (keeps hi/lo frags short-lived)
#pragma unroll
    for (int rt = 0; rt < 4; ++rt) {
      float vv[8] = {ca[rt][0].x, ca[rt][0].y, ca[rt][0].z, ca[rt][0].w,
                     ca[rt][1].x, ca[rt][1].y, ca[rt][1].z, ca[rt][1].w};
      half8 hh, hl;
#pragma unroll
      for (int j = 0; j < 8; ++j) {
        _Float16 h = (_Float16)vv[j];
        hh[j] = h;
        hl[j] = (_Float16)(vv[j] - (float)h);
      }
#pragma unroll
      for (int ct = 0; ct < 4; ++ct) {
        acc[rt][ct] = __builtin_amdgcn_mfma_f32_16x16x32_f16(hh, bf[ct], acc[rt][ct], 0, 0, 0);
        acc[rt][ct] = __builtin_amdgcn_mfma_f32_16x16x32_f16(hl, bf[ct], acc[rt][ct], 0, 0, 0);
      }
    }
  }

  float vmin = 3.4e38f, vmax = -3.4e38f;
#pragma unroll
  for (int rt = 0; rt < 4; ++rt)
#pragma unroll
    for (int ct = 0; ct < 4; ++ct) {
      f32x4v c = acc[rt][ct];
      const int col = wave * 64 + ct * 16 + nn;
      const int sl = s0 + rt * 16 + quad * 4;
      *(float4*)&MT[((size_t)el * F_ + col) * S_ + sl] =
          make_float4(c[0], c[1], c[2], c[3]);
      vmin = fminf(vmin, fminf(fminf(c[0], c[1]), fminf(c[2], c[3])));
      vmax = fmaxf(vmax, fmaxf(fmaxf(c[0], c[1]), fmaxf(c[2], c[3])));
    }
#pragma unroll
  for (int off = 32; off; off >>= 1) {
    vmin = fminf(vmin, __shfl_down(vmin, off));
    vmax = fmaxf(vmax, __shfl_down(vmax, off));
  }
  if (lane == 0) {
    atomicMin(&slots[0], encf(vmin));
    atomicMax(&slots[1], encf(vmax));
  }
}

// K1: grid + Fourier constants.
__global__ __launch_bounds__(64) void k1_setup(const unsigned int* __restrict__ slots,
                                               float* __restrict__ hdr) {
  if (threadIdx.x == 0) {
    const float left = decf(slots[0]);
    const float right = decf(slots[1]);
    const float dg = (right - left) / 1023.0f;
    const float delta = (right - left) / 1024.0f;
    const float divisor = 0.62665706865775006f;   // sqrt(2*pi)*0.25
    const float scale = delta * 0.5f / divisor;
    const float Pp = (right - left) + 5.0f;       // period (alias gap > 2.4)
    const float sqpi8 = 0.62665706865775006f;     // sqrt(pi/8)
    hdr[0] = left; hdr[1] = dg; hdr[2] = 0.f; hdr[3] = scale;
    hdr[4] = 6.2831853071795864f / Pp;            // omega1
    hdr[5] = 2.0f * sqpi8 / Pp;                   // a_k scale
    hdr[6] = sqpi8 / Pp;                          // a_0
  }
}

// KB: basis matrix BT[t][j], j=2*kidx(+1): kidx 0=DC, 1..48=a_k cos(w_k x_t),
// 49..96=a_k sin. Both hi/lo slots carry the same value (CS carries hi/lo).
__global__ __launch_bounds__(256) void kB(const float* __restrict__ hdr,
                                          _Float16* __restrict__ BT) {
  const int t = blockIdx.x;
  const int j = threadIdx.x;
  if (j >= CSW) return;
  const float left = hdr[0], dg = hdr[1];
  const float w1 = hdr[4], asc = hdr[5], a0 = hdr[6];
  const float x = left + (float)t * dg;
  float v = 0.f;
  const int kidx = j >> 1;
  if (j < 2 * (2 * NH + 1)) {
    if (kidx == 0) v = a0;
    else if (kidx <= NH) {
      float wk = w1 * (float)kidx;
      v = asc * expf(-wk * wk * 0.03125f) * __cosf(wk * x);
    } else {
      float wk = w1 * (float)(kidx - NH);
      v = asc * expf(-wk * wk * 0.03125f) * __sinf(wk * x);
    }
  }
  BT[(size_t)t * CSW + j] = (_Float16)v;
}

// KF: Fourier sums C_k(f)=sum_s cos(w_k m), S_k likewise. Single pass,
// 48 harmonics, Chebyshev 3-term recurrence PACKED into float2 lanes
// (cos chain in .x, sin chain in .y -> v_pk_fma_f32 / v_pk_add_f32),
// one sincos per sample, explicit prefetch of next float4, width-32
// shuffle reduction. No atomics, no LDS.
__global__ __launch_bounds__(256) void kF(const float* __restrict__ MT,
                                          const float* __restrict__ hdr,
                                          _Float16* __restrict__ CS) {
  const int tid = threadIdx.x;
  const int floc = tid >> 5, slice = tid & 31;
  const int el = blockIdx.x >> 5;
  const int fg = blockIdx.x & 31;
  const int f = fg * 8 + floc;
  const float w1 = hdr[4];
  const float* src = MT + ((size_t)el * F_ + f) * S_ + slice * 32;
  _Float16* csrow = CS + ((size_t)el * F_ + f) * CSW;
  f32x2 acc[NH];
#pragma unroll
  for (int k = 0; k < NH; ++k) acc[k] = (f32x2){0.f, 0.f};
  float4 nxt = ((const float4*)src)[0];
  for (int it = 0; it < 8; ++it) {
    float4 cur = nxt;
    if (it < 7) nxt = ((const float4*)src)[it + 1];   // prefetch next tile
    float mv[4] = {cur.x, cur.y, cur.z, cur.w};
#pragma unroll
    for (int c = 0; c < 4; ++c) {
      float al = w1 * mv[c];
      float s1, c1;
      __sincosf(al, &s1, &c1);
      const float tc = 2.f * c1;
      f32x2 tc2; tc2[0] = tc; tc2[1] = tc;
      f32x2 p;  p[0] = c1;  p[1] = s1;    // current (cos k*a, sin k*a)
      f32x2 pp; pp[0] = 1.f; pp[1] = 0.f; // previous (k-1)
      acc[0] += p;
#pragma unroll
      for (int k = 1; k < NH; ++k) {
        f32x2 n = tc2 * p - pp;           // packed Chebyshev step (1 pk_fma)
        acc[k] += n;                      // packed accumulate (1 pk_add)
        pp = p; p = n;
      }
    }
  }
#pragma unroll
  for (int off = 16; off; off >>= 1)
#pragma unroll
    for (int k = 0; k < NH; ++k) {
      acc[k][0] += __shfl_down(acc[k][0], off, 32);
      acc[k][1] += __shfl_down(acc[k][1], off, 32);
    }
  if (slice == 0) {
    csrow[0] = (_Float16)1024.f;   // DC: C_0 = S count (exact)
    csrow[1] = (_Float16)0.f;
#pragma unroll
    for (int k = 0; k < NH; ++k) {
      put_hl(csrow + 2 * (1 + k), acc[k][0]);        // cos harmonics 1..48
      put_hl(csrow + 2 * (NH + 1 + k), acc[k][1]);   // sin harmonics 1..48
    }
  }
}

// KR: reconstruction GEMM ksum = CS x BT^T via MFMA (7 K-chunks of 32).
// R2: ZERO-LDS / ZERO-BARRIER, same direct-fragment-load transform as k0.
// CS rows are 16B-aligned (CSW=224 halves = 448B); BT likewise.
__global__ __launch_bounds__(256) void kR(const _Float16* __restrict__ CS,
                                          const _Float16* __restrict__ BT,
                                          float* __restrict__ OUT) {
  const int tid = threadIdx.x;
  const int wave = tid >> 6, lane = tid & 63;
  const int nn = lane & 15, quad = lane >> 4;
  const int el = blockIdx.x >> 4;
  const int t0 = (blockIdx.x & 15) << 6;

  const _Float16* ab0 = CS + ((size_t)el * F_ + wave * 64 + 0 * 16 + nn) * CSW + quad * 8;
  const _Float16* ab1 = CS + ((size_t)el * F_ + wave * 64 + 1 * 16 + nn) * CSW + quad * 8;
  const _Float16* ab2 = CS + ((size_t)el * F_ + wave * 64 + 2 * 16 + nn) * CSW + quad * 8;
  const _Float16* ab3 = CS + ((size_t)el * F_ + wave * 64 + 3 * 16 + nn) * CSW + quad * 8;
  const _Float16* bb0 = BT + (size_t)(t0 + 0 * 16 + nn) * CSW + quad * 8;
  const _Float16* bb1 = BT + (size_t)(t0 + 1 * 16 + nn) * CSW + quad * 8;
  const _Float16* bb2 = BT + (size_t)(t0 + 2 * 16 + nn) * CSW + quad * 8;
  const _Float16* bb3 = BT + (size_t)(t0 + 3 * 16 + nn) * CSW + quad * 8;

  f32x4v acc[4][4];
#pragma unroll
  for (int ft = 0; ft < 4; ++ft)
#pragma unroll
    for (int tn = 0; tn < 4; ++tn) acc[ft][tn] = (f32x4v){0.f, 0.f, 0.f, 0.f};

  half8 pa[4], pb[4];
  pa[0] = *(const half8*)ab0; pa[1] = *(const half8*)ab1;
  pa[2] = *(const half8*)ab2; pa[3] = *(const half8*)ab3;
  pb[0] = *(const half8*)bb0; pb[1] = *(const half8*)bb1;
  pb[2] = *(const half8*)bb2; pb[3] = *(const half8*)bb3;

#pragma unroll
  for (int kc = 0; kc < CSW / 32; ++kc) {
    half8 af[4], bf[4];
#pragma unroll
    for (int ft = 0; ft < 4; ++ft) af[ft] = pa[ft];
#pragma unroll
    for (int tn = 0; tn < 4; ++tn) bf[tn] = pb[tn];
    if (kc < CSW / 32 - 1) {
      const int o = (kc + 1) * 32;
      pa[0] = *(const half8*)(ab0 + o); pa[1] = *(const half8*)(ab1 + o);
      pa[2] = *(const half8*)(ab2 + o); pa[3] = *(const half8*)(ab3 + o);
      pb[0] = *(const half8*)(bb0 + o); pb[1] = *(const half8*)(bb1 + o);
      pb[2] = *(const half8*)(bb2 + o); pb[3] = *(const half8*)(bb3 + o);
    }
#pragma unroll
    for (int ft = 0; ft < 4; ++ft)
#pragma unroll
      for (int tn = 0; tn < 4; ++tn)
        acc[ft][tn] = __builtin_amdgcn_mfma_f32_16x16x32_f16(af[ft], bf[tn], acc[ft][tn], 0, 0, 0);
  }

  float* Ob = OUT + (size_t)el * F_ * T_ + t0;
#pragma unroll
  for (int ft = 0; ft < 4; ++ft)
#pragma unroll
    for (int tn = 0; tn < 4; ++tn) {
      f32x4v c = acc[ft][tn];
      const int fb = wave * 64 + ft * 16 + quad * 4;
      const int tc = tn * 16 + nn;
      Ob[(size_t)(fb + 0) * T_ + tc] = c[0];
      Ob[(size_t)(fb + 1) * T_ + tc] = c[1];
      Ob[(size_t)(fb + 2) * T_ + tc] = c[2];
      Ob[(size_t)(fb + 3) * T_ + tc] = c[3];
    }
}

// K4: epilogue (unchanged, validated).
__global__ __launch_bounds__(256) void k4_epi(const float* __restrict__ OUT,
                                              const float* __restrict__ hdr,
                                              const float* __restrict__ dl,
                                              float* __restrict__ out) {
  __shared__ float rs[4][6];
  const int tid = threadIdx.x;
  const int l = blockIdx.x >> 8;
  const int f = blockIdx.x & 255;
  const float left = hdr[0], dg = hdr[1], scale = hdr[3];
  const int t = 4 * tid;
  float etv[4];
#pragma unroll
  for (int d = 0; d < 4; ++d) {
    float x = left + (float)(t + d) * dg;
    etv[d] = expf(-8.0f * x * x);
  }
  float red[E_][4];
#pragma unroll
  for (int e = 0; e < E_; ++e) {
    float4 ks = *(const float4*)(OUT + (((size_t)(e * L_ + l)) * F_ + f) * T_ + t);
    const float dlv = dl[e * L_ + l];
    const float zc = (float)S_ - dlv;
    const float idl = 1.0f / dlv;
    red[e][0] = (ks.x - zc * etv[0]) * idl;
    red[e][1] = (ks.y - zc * etv[1]) * idl;
    red[e][2] = (ks.z - zc * etv[2]) * idl;
    red[e][3] = (ks.w - zc * etv[3]) * idl;
  }
  float D[6];
  const int pa[6] = {0, 0, 0, 1, 1, 2};
  const int pb[6] = {1, 2, 3, 2, 3, 3};
#pragma unroll
  for (int p = 0; p < 6; ++p) {
    float s = 0.f;
#pragma unroll
    for (int d = 0; d < 4; ++d) s += fabsf(red[pa[p]][d] - red[pb[p]][d]);
    D[p] = s;
  }
#pragma unroll
  for (int off = 32; off; off >>= 1)
#pragma unroll
    for (int p = 0; p < 6; ++p) D[p] += __shfl_down(D[p], off);
  if ((tid & 63) == 0) {
#pragma unroll
    for (int p = 0; p < 6; ++p) rs[tid >> 6][p] = D[p];
  }
  __syncthreads();
  if (tid == 0) {
    float Tp[6];
#pragma unroll
    for (int p = 0; p < 6; ++p)
      Tp[p] = (rs[0][p] + rs[1][p] + rs[2][p] + rs[3][p]) * scale;
    float test = Tp[0];
#pragma unroll
    for (int p = 1; p < 6; ++p) test = fmaxf(test, Tp[p]);
    float train = fmaxf(fmaxf(Tp[1], Tp[2]), Tp[5]);
    out[l * F_ + f] = train;
    out[L_ * F_ + l * F_ + f] = test;
  }
}

extern "C" void kernel_launch(void* const* d_in, const int* in_sizes, int n_in,
                              void* d_out, int out_size, void* d_ws, size_t ws_size,
                              hipStream_t stream) {
  const float* A  = (const float*)d_in[0];   // matrix (4,10,1024,256)
  const float* dl = (const float*)d_in[1];   // data_len (4,10)
  const float* P  = (const float*)d_in[2];   // params (256,256)
  float* out = (float*)d_out;
  float* ws = (float*)d_ws;
  float* hdr = ws;
  unsigned int* slots = (unsigned int*)(ws + 16);
  float* MT  = ws + OFF_M;                   // fp32 GEMM result (dead after kF)
  float* OUT = ws + OFF_M;                   // OUT aliases MT
  _Float16* CS = (_Float16*)(ws + OFF_CS);
  _Float16* BT = (_Float16*)(ws + OFF_BT);
  _Float16* PT = (_Float16*)(ws + OFF_PT);

  // Determinism under 0xAA ws-poison: zero all f16 regions (pads included).
  (void)hipMemsetAsync(CS, 0, (size_t)40 * F_ * CSW * 2, stream);   // 4.6 MB
  (void)hipMemsetAsync(BT, 0, (size_t)T_ * CSW * 2, stream);
  (void)hipMemsetAsync(PT, 0, (size_t)F_ * F_ * 2, stream);
  (void)hipMemsetAsync(slots, 0xFF, 4, stream);      // min slot neutral
  (void)hipMemsetAsync(slots + 1, 0x00, 4, stream);  // max slot neutral

  k_pt<<<F_, 256, 0, stream>>>(P, PT);
  k0_mfma<<<NROW / 64, 256, 0, stream>>>(A, PT, MT, slots);
  k1_setup<<<1, 64, 0, stream>>>(slots, hdr);
  kB<<<T_, 256, 0, stream>>>(hdr, BT);
  kF<<<(E_ * L_) * 32, 256, 0, stream>>>(MT, hdr, CS);
  kR<<<(E_ * L_) * 16, 256, 0, stream>>>(CS, BT, OUT);
  k4_epi<<<L_ * F_, 256, 0, stream>>>(OUT, hdr, dl, out);
}

// Round 4
// 205.043 us; speedup vs baseline: 1.2523x; 1.2523x over previous
//
#include <hip/hip_runtime.h>
#include <hip/hip_fp16.h>
#include <math.h>

// Problem constants (fixed by reference setup_inputs)
#define E_ 4
#define L_ 10
#define S_ 1024
#define F_ 256
#define T_ 1024
#define NROW (E_*L_*S_)     // 40960 rows of the input GEMM
#define NBLK (NROW/64)      // 640 k0 blocks -> per-block min/max partials
#define NH   48             // Fourier harmonics (cos+sin each); tail e^-11.1
#define CSW  224            // padded CS/BT row width in halves (194 live + pad)

// workspace layout (float indices). OUT aliases MT (MT dead after kF).
// ws+0..15: hdr. ws+64..: pmin[640]. ws+768..: pmax[640].
#define OFF_PMIN 64
#define OFF_PMAX 768
#define OFF_M   32768                          // fp32 MT[el][f][s] (= OUT alias)
#define OFF_CS  (32768 + (size_t)NROW * F_)    // f16 CS[el][f][CSW] hi/lo pairs
#define OFF_BT  (OFF_CS + (size_t)40 * F_ * CSW / 2)   // f16 BT[t][CSW]
#define OFF_PT  (OFF_BT + (size_t)T_ * CSW / 2)        // f16 PT[256][256]

typedef _Float16 half8 __attribute__((ext_vector_type(8)));
typedef float f32x4v __attribute__((ext_vector_type(4)));
typedef float f32x2 __attribute__((ext_vector_type(2)));

__device__ __forceinline__ void put_hl(_Float16* p, float v) {
  _Float16 h = (_Float16)v;
  _Float16 l = (_Float16)(v - (float)h);
  p[0] = h; p[1] = l;
}

// K_pt: PT[c][k] = (f16)P[k][c].
__global__ __launch_bounds__(256) void k_pt(const float* __restrict__ P,
                                            _Float16* __restrict__ PT) {
  const int k = blockIdx.x;
  const int c = threadIdx.x;
  PT[(size_t)c * F_ + k] = (_Float16)P[(size_t)k * F_ + c];
}

// K0: m = matrix @ params via MFMA f16 hi/lo split; writes M TRANSPOSED:
// MT[el][f][s].
// R3: R1 pipeline (LDS staging + 1-chunk register prefetch) + ZERO global
// atomics: per-block min/max partials stored to pmin/pmax (640 plain
// stores); k1_setup does the final reduction. Theory: the 2560-wave
// same-cache-line atomicMin/Max tail was the common ~80 us floor across
// all three pipeline variants (all pipes idle, dur >> busy).
__global__ __launch_bounds__(256) void k0_mfma(const float* __restrict__ A,
                                               const _Float16* __restrict__ PT,
                                               float* __restrict__ MT,
                                               float* __restrict__ pmin,
                                               float* __restrict__ pmax) {
  __shared__ __align__(16) _Float16 Ahi[64][40];
  __shared__ __align__(16) _Float16 Alo[64][40];
  __shared__ __align__(16) _Float16 Bl[256][40];
  __shared__ float wmin[4], wmax[4];
  const int tid = threadIdx.x;
  const int wave = tid >> 6, lane = tid & 63;
  const int nn = lane & 15, quad = lane >> 4;
  const int row0 = blockIdx.x * 64;
  const int el = blockIdx.x >> 4;
  const int s0 = (blockIdx.x & 15) * 64;
  const int r = tid >> 2, part = tid & 3;
  const float* asrc = A + (size_t)(row0 + r) * F_ + part * 8;
  const _Float16* bbase = PT + (size_t)tid * F_;
  f32x4v acc[4][4];
#pragma unroll
  for (int rt = 0; rt < 4; ++rt)
#pragma unroll
    for (int ct = 0; ct < 4; ++ct) acc[rt][ct] = (f32x4v){0.f, 0.f, 0.f, 0.f};

  // prefetch chunk 0 into registers
  float4 pa0 = ((const float4*)asrc)[0];
  float4 pa1 = ((const float4*)asrc)[1];
  int4 pb0, pb1, pb2, pb3;
  {
    const int4* bs = (const int4*)bbase;
    pb0 = bs[0]; pb1 = bs[1]; pb2 = bs[2]; pb3 = bs[3];
  }

  for (int kc = 0; kc < 8; ++kc) {
    __syncthreads();   // prior chunk's fragment reads complete; LDS reusable
    // stage current chunk from prefetch registers (convert f32 -> f16 hi/lo)
    {
      float vv[8] = {pa0.x, pa0.y, pa0.z, pa0.w, pa1.x, pa1.y, pa1.z, pa1.w};
      half8 hh, hl;
#pragma unroll
      for (int j = 0; j < 8; ++j) {
        _Float16 h = (_Float16)vv[j];
        hh[j] = h;
        hl[j] = (_Float16)(vv[j] - (float)h);
      }
      *(half8*)&Ahi[r][part * 8] = hh;
      *(half8*)&Alo[r][part * 8] = hl;
      int4* bd = (int4*)&Bl[tid][0];
      bd[0] = pb0; bd[1] = pb1; bd[2] = pb2; bd[3] = pb3;
    }
    // issue next chunk's loads NOW: in flight across ds_reads + MFMAs,
    // first consumed after the next top-of-loop barrier.
    if (kc < 7) {
      const float* an = asrc + (kc + 1) * 32;
      pa0 = ((const float4*)an)[0];
      pa1 = ((const float4*)an)[1];
      const int4* bn = (const int4*)(bbase + (kc + 1) * 32);
      pb0 = bn[0]; pb1 = bn[1]; pb2 = bn[2]; pb3 = bn[3];
    }
    __syncthreads();   // LDS tile visible
    half8 afh[4], afl[4], bf[4];
#pragma unroll
    for (int rt = 0; rt < 4; ++rt) {
      afh[rt] = *(const half8*)&Ahi[rt * 16 + nn][quad * 8];
      afl[rt] = *(const half8*)&Alo[rt * 16 + nn][quad * 8];
    }
#pragma unroll
    for (int ct = 0; ct < 4; ++ct)
      bf[ct] = *(const half8*)&Bl[wave * 64 + ct * 16 + nn][quad * 8];
#pragma unroll
    for (int rt = 0; rt < 4; ++rt)
#pragma unroll
      for (int ct = 0; ct < 4; ++ct) {
        acc[rt][ct] = __builtin_amdgcn_mfma_f32_16x16x32_f16(afh[rt], bf[ct], acc[rt][ct], 0, 0, 0);
        acc[rt][ct] = __builtin_amdgcn_mfma_f32_16x16x32_f16(afl[rt], bf[ct], acc[rt][ct], 0, 0, 0);
      }
  }
  float vmin = 3.4e38f, vmax = -3.4e38f;
#pragma unroll
  for (int rt = 0; rt < 4; ++rt)
#pragma unroll
    for (int ct = 0; ct < 4; ++ct) {
      f32x4v c = acc[rt][ct];
      const int col = wave * 64 + ct * 16 + nn;
      const int sl = s0 + rt * 16 + quad * 4;
      *(float4*)&MT[((size_t)el * F_ + col) * S_ + sl] =
          make_float4(c[0], c[1], c[2], c[3]);
      vmin = fminf(vmin, fminf(fminf(c[0], c[1]), fminf(c[2], c[3])));
      vmax = fmaxf(vmax, fmaxf(fmaxf(c[0], c[1]), fmaxf(c[2], c[3])));
    }
#pragma unroll
  for (int off = 32; off; off >>= 1) {
    vmin = fminf(vmin, __shfl_down(vmin, off));
    vmax = fmaxf(vmax, __shfl_down(vmax, off));
  }
  if (lane == 0) { wmin[wave] = vmin; wmax[wave] = vmax; }
  __syncthreads();
  if (tid == 0) {
    pmin[blockIdx.x] = fminf(fminf(wmin[0], wmin[1]), fminf(wmin[2], wmin[3]));
    pmax[blockIdx.x] = fmaxf(fmaxf(wmax[0], wmax[1]), fmaxf(wmax[2], wmax[3]));
  }
}

// K1: final min/max reduction over 640 per-block partials + grid/Fourier
// constants. Single block, 256 threads — replaces all global atomics.
__global__ __launch_bounds__(256) void k1_setup(const float* __restrict__ pmin,
                                                const float* __restrict__ pmax,
                                                float* __restrict__ hdr) {
  __shared__ float sm[4], sx[4];
  const int tid = threadIdx.x;
  float vmin = 3.4e38f, vmax = -3.4e38f;
  for (int i = tid; i < NBLK; i += 256) {
    vmin = fminf(vmin, pmin[i]);
    vmax = fmaxf(vmax, pmax[i]);
  }
#pragma unroll
  for (int off = 32; off; off >>= 1) {
    vmin = fminf(vmin, __shfl_down(vmin, off));
    vmax = fmaxf(vmax, __shfl_down(vmax, off));
  }
  if ((tid & 63) == 0) { sm[tid >> 6] = vmin; sx[tid >> 6] = vmax; }
  __syncthreads();
  if (tid == 0) {
    const float left = fminf(fminf(sm[0], sm[1]), fminf(sm[2], sm[3]));
    const float right = fmaxf(fmaxf(sx[0], sx[1]), fmaxf(sx[2], sx[3]));
    const float dg = (right - left) / 1023.0f;
    const float delta = (right - left) / 1024.0f;
    const float divisor = 0.62665706865775006f;   // sqrt(2*pi)*0.25
    const float scale = delta * 0.5f / divisor;
    const float Pp = (right - left) + 5.0f;       // period (alias gap > 2.4)
    const float sqpi8 = 0.62665706865775006f;     // sqrt(pi/8)
    hdr[0] = left; hdr[1] = dg; hdr[2] = 0.f; hdr[3] = scale;
    hdr[4] = 6.2831853071795864f / Pp;            // omega1
    hdr[5] = 2.0f * sqpi8 / Pp;                   // a_k scale
    hdr[6] = sqpi8 / Pp;                          // a_0
  }
}

// KB: basis matrix BT[t][j], j=2*kidx(+1): kidx 0=DC, 1..48=a_k cos(w_k x_t),
// 49..96=a_k sin. Both hi/lo slots carry the same value (CS carries hi/lo).
__global__ __launch_bounds__(256) void kB(const float* __restrict__ hdr,
                                          _Float16* __restrict__ BT) {
  const int t = blockIdx.x;
  const int j = threadIdx.x;
  if (j >= CSW) return;
  const float left = hdr[0], dg = hdr[1];
  const float w1 = hdr[4], asc = hdr[5], a0 = hdr[6];
  const float x = left + (float)t * dg;
  float v = 0.f;
  const int kidx = j >> 1;
  if (j < 2 * (2 * NH + 1)) {
    if (kidx == 0) v = a0;
    else if (kidx <= NH) {
      float wk = w1 * (float)kidx;
      v = asc * expf(-wk * wk * 0.03125f) * __cosf(wk * x);
    } else {
      float wk = w1 * (float)(kidx - NH);
      v = asc * expf(-wk * wk * 0.03125f) * __sinf(wk * x);
    }
  }
  BT[(size_t)t * CSW + j] = (_Float16)v;
}

// KF: Fourier sums C_k(f)=sum_s cos(w_k m), S_k likewise. Single pass,
// 48 harmonics, Chebyshev 3-term recurrence PACKED into float2 lanes
// (cos chain in .x, sin chain in .y -> v_pk_fma_f32 / v_pk_add_f32),
// one sincos per sample, explicit prefetch of next float4, width-32
// shuffle reduction. No atomics, no LDS.
__global__ __launch_bounds__(256) void kF(const float* __restrict__ MT,
                                          const float* __restrict__ hdr,
                                          _Float16* __restrict__ CS) {
  const int tid = threadIdx.x;
  const int floc = tid >> 5, slice = tid & 31;
  const int el = blockIdx.x >> 5;
  const int fg = blockIdx.x & 31;
  const int f = fg * 8 + floc;
  const float w1 = hdr[4];
  const float* src = MT + ((size_t)el * F_ + f) * S_ + slice * 32;
  _Float16* csrow = CS + ((size_t)el * F_ + f) * CSW;
  f32x2 acc[NH];
#pragma unroll
  for (int k = 0; k < NH; ++k) acc[k] = (f32x2){0.f, 0.f};
  float4 nxt = ((const float4*)src)[0];
  for (int it = 0; it < 8; ++it) {
    float4 cur = nxt;
    if (it < 7) nxt = ((const float4*)src)[it + 1];   // prefetch next tile
    float mv[4] = {cur.x, cur.y, cur.z, cur.w};
#pragma unroll
    for (int c = 0; c < 4; ++c) {
      float al = w1 * mv[c];
      float s1, c1;
      __sincosf(al, &s1, &c1);
      const float tc = 2.f * c1;
      f32x2 tc2; tc2[0] = tc; tc2[1] = tc;
      f32x2 p;  p[0] = c1;  p[1] = s1;    // current (cos k*a, sin k*a)
      f32x2 pp; pp[0] = 1.f; pp[1] = 0.f; // previous (k-1)
      acc[0] += p;
#pragma unroll
      for (int k = 1; k < NH; ++k) {
        f32x2 n = tc2 * p - pp;           // packed Chebyshev step (1 pk_fma)
        acc[k] += n;                      // packed accumulate (1 pk_add)
        pp = p; p = n;
      }
    }
  }
#pragma unroll
  for (int off = 16; off; off >>= 1)
#pragma unroll
    for (int k = 0; k < NH; ++k) {
      acc[k][0] += __shfl_down(acc[k][0], off, 32);
      acc[k][1] += __shfl_down(acc[k][1], off, 32);
    }
  if (slice == 0) {
    csrow[0] = (_Float16)1024.f;   // DC: C_0 = S count (exact)
    csrow[1] = (_Float16)0.f;
#pragma unroll
    for (int k = 0; k < NH; ++k) {
      put_hl(csrow + 2 * (1 + k), acc[k][0]);        // cos harmonics 1..48
      put_hl(csrow + 2 * (NH + 1 + k), acc[k][1]);   // sin harmonics 1..48
    }
  }
}

// KR: reconstruction GEMM ksum = CS x BT^T via MFMA (7 K-chunks of 32).
// R2: ZERO-LDS / ZERO-BARRIER, direct-fragment-load (16B-aligned rows).
__global__ __launch_bounds__(256) void kR(const _Float16* __restrict__ CS,
                                          const _Float16* __restrict__ BT,
                                          float* __restrict__ OUT) {
  const int tid = threadIdx.x;
  const int wave = tid >> 6, lane = tid & 63;
  const int nn = lane & 15, quad = lane >> 4;
  const int el = blockIdx.x >> 4;
  const int t0 = (blockIdx.x & 15) << 6;

  const _Float16* ab0 = CS + ((size_t)el * F_ + wave * 64 + 0 * 16 + nn) * CSW + quad * 8;
  const _Float16* ab1 = CS + ((size_t)el * F_ + wave * 64 + 1 * 16 + nn) * CSW + quad * 8;
  const _Float16* ab2 = CS + ((size_t)el * F_ + wave * 64 + 2 * 16 + nn) * CSW + quad * 8;
  const _Float16* ab3 = CS + ((size_t)el * F_ + wave * 64 + 3 * 16 + nn) * CSW + quad * 8;
  const _Float16* bb0 = BT + (size_t)(t0 + 0 * 16 + nn) * CSW + quad * 8;
  const _Float16* bb1 = BT + (size_t)(t0 + 1 * 16 + nn) * CSW + quad * 8;
  const _Float16* bb2 = BT + (size_t)(t0 + 2 * 16 + nn) * CSW + quad * 8;
  const _Float16* bb3 = BT + (size_t)(t0 + 3 * 16 + nn) * CSW + quad * 8;

  f32x4v acc[4][4];
#pragma unroll
  for (int ft = 0; ft < 4; ++ft)
#pragma unroll
    for (int tn = 0; tn < 4; ++tn) acc[ft][tn] = (f32x4v){0.f, 0.f, 0.f, 0.f};

  half8 pa[4], pb[4];
  pa[0] = *(const half8*)ab0; pa[1] = *(const half8*)ab1;
  pa[2] = *(const half8*)ab2; pa[3] = *(const half8*)ab3;
  pb[0] = *(const half8*)bb0; pb[1] = *(const half8*)bb1;
  pb[2] = *(const half8*)bb2; pb[3] = *(const half8*)bb3;

#pragma unroll
  for (int kc = 0; kc < CSW / 32; ++kc) {
    half8 af[4], bf[4];
#pragma unroll
    for (int ft = 0; ft < 4; ++ft) af[ft] = pa[ft];
#pragma unroll
    for (int tn = 0; tn < 4; ++tn) bf[tn] = pb[tn];
    if (kc < CSW / 32 - 1) {
      const int o = (kc + 1) * 32;
      pa[0] = *(const half8*)(ab0 + o); pa[1] = *(const half8*)(ab1 + o);
      pa[2] = *(const half8*)(ab2 + o); pa[3] = *(const half8*)(ab3 + o);
      pb[0] = *(const half8*)(bb0 + o); pb[1] = *(const half8*)(bb1 + o);
      pb[2] = *(const half8*)(bb2 + o); pb[3] = *(const half8*)(bb3 + o);
    }
#pragma unroll
    for (int ft = 0; ft < 4; ++ft)
#pragma unroll
      for (int tn = 0; tn < 4; ++tn)
        acc[ft][tn] = __builtin_amdgcn_mfma_f32_16x16x32_f16(af[ft], bf[tn], acc[ft][tn], 0, 0, 0);
  }

  float* Ob = OUT + (size_t)el * F_ * T_ + t0;
#pragma unroll
  for (int ft = 0; ft < 4; ++ft)
#pragma unroll
    for (int tn = 0; tn < 4; ++tn) {
      f32x4v c = acc[ft][tn];
      const int fb = wave * 64 + ft * 16 + quad * 4;
      const int tc = tn * 16 + nn;
      Ob[(size_t)(fb + 0) * T_ + tc] = c[0];
      Ob[(size_t)(fb + 1) * T_ + tc] = c[1];
      Ob[(size_t)(fb + 2) * T_ + tc] = c[2];
      Ob[(size_t)(fb + 3) * T_ + tc] = c[3];
    }
}

// K4: epilogue (unchanged, validated).
__global__ __launch_bounds__(256) void k4_epi(const float* __restrict__ OUT,
                                              const float* __restrict__ hdr,
                                              const float* __restrict__ dl,
                                              float* __restrict__ out) {
  __shared__ float rs[4][6];
  const int tid = threadIdx.x;
  const int l = blockIdx.x >> 8;
  const int f = blockIdx.x & 255;
  const float left = hdr[0], dg = hdr[1], scale = hdr[3];
  const int t = 4 * tid;
  float etv[4];
#pragma unroll
  for (int d = 0; d < 4; ++d) {
    float x = left + (float)(t + d) * dg;
    etv[d] = expf(-8.0f * x * x);
  }
  float red[E_][4];
#pragma unroll
  for (int e = 0; e < E_; ++e) {
    float4 ks = *(const float4*)(OUT + (((size_t)(e * L_ + l)) * F_ + f) * T_ + t);
    const float dlv = dl[e * L_ + l];
    const float zc = (float)S_ - dlv;
    const float idl = 1.0f / dlv;
    red[e][0] = (ks.x - zc * etv[0]) * idl;
    red[e][1] = (ks.y - zc * etv[1]) * idl;
    red[e][2] = (ks.z - zc * etv[2]) * idl;
    red[e][3] = (ks.w - zc * etv[3]) * idl;
  }
  float D[6];
  const int pa[6] = {0, 0, 0, 1, 1, 2};
  const int pb[6] = {1, 2, 3, 2, 3, 3};
#pragma unroll
  for (int p = 0; p < 6; ++p) {
    float s = 0.f;
#pragma unroll
    for (int d = 0; d < 4; ++d) s += fabsf(red[pa[p]][d] - red[pb[p]][d]);
    D[p] = s;
  }
#pragma unroll
  for (int off = 32; off; off >>= 1)
#pragma unroll
    for (int p = 0; p < 6; ++p) D[p] += __shfl_down(D[p], off);
  if ((tid & 63) == 0) {
#pragma unroll
    for (int p = 0; p < 6; ++p) rs[tid >> 6][p] = D[p];
  }
  __syncthreads();
  if (tid == 0) {
    float Tp[6];
#pragma unroll
    for (int p = 0; p < 6; ++p)
      Tp[p] = (rs[0][p] + rs[1][p] + rs[2][p] + rs[3][p]) * scale;
    float test = Tp[0];
#pragma unroll
    for (int p = 1; p < 6; ++p) test = fmaxf(test, Tp[p]);
    float train = fmaxf(fmaxf(Tp[1], Tp[2]), Tp[5]);
    out[l * F_ + f] = train;
    out[L_ * F_ + l * F_ + f] = test;
  }
}

extern "C" void kernel_launch(void* const* d_in, const int* in_sizes, int n_in,
                              void* d_out, int out_size, void* d_ws, size_t ws_size,
                              hipStream_t stream) {
  const float* A  = (const float*)d_in[0];   // matrix (4,10,1024,256)
  const float* dl = (const float*)d_in[1];   // data_len (4,10)
  const float* P  = (const float*)d_in[2];   // params (256,256)
  float* out = (float*)d_out;
  float* ws = (float*)d_ws;
  float* hdr = ws;
  float* pmin = ws + OFF_PMIN;               // 640 per-block minima
  float* pmax = ws + OFF_PMAX;               // 640 per-block maxima
  float* MT  = ws + OFF_M;                   // fp32 GEMM result (dead after kF)
  float* OUT = ws + OFF_M;                   // OUT aliases MT
  _Float16* CS = (_Float16*)(ws + OFF_CS);
  _Float16* BT = (_Float16*)(ws + OFF_BT);
  _Float16* PT = (_Float16*)(ws + OFF_PT);

  // Determinism under 0xAA ws-poison: zero all f16 regions (pads included).
  // pmin/pmax need no clearing: every element written by k0 before k1 reads.
  (void)hipMemsetAsync(CS, 0, (size_t)40 * F_ * CSW * 2, stream);   // 4.6 MB
  (void)hipMemsetAsync(BT, 0, (size_t)T_ * CSW * 2, stream);
  (void)hipMemsetAsync(PT, 0, (size_t)F_ * F_ * 2, stream);

  k_pt<<<F_, 256, 0, stream>>>(P, PT);
  k0_mfma<<<NBLK, 256, 0, stream>>>(A, PT, MT, pmin, pmax);
  k1_setup<<<1, 256, 0, stream>>>(pmin, pmax, hdr);
  kB<<<T_, 256, 0, stream>>>(hdr, BT);
  kF<<<(E_ * L_) * 32, 256, 0, stream>>>(MT, hdr, CS);
  kR<<<(E_ * L_) * 16, 256, 0, stream>>>(CS, BT, OUT);
  k4_epi<<<L_ * F_, 256, 0, stream>>>(OUT, hdr, dl, out);
}

// Round 5
// 197.497 us; speedup vs baseline: 1.3001x; 1.0382x over previous
//
#include <hip/hip_runtime.h>
#include <hip/hip_fp16.h>
#include <math.h>

// Problem constants (fixed by reference setup_inputs)
#define E_ 4
#define L_ 10
#define S_ 1024
#define F_ 256
#define T_ 1024
#define NROW (E_*L_*S_)     // 40960 rows of the input GEMM
#define NBLK (NROW/64)      // 640 k0 blocks -> per-block min/max partials
#define NH   48             // Fourier harmonics (cos+sin each); tail e^-11.1
#define CSW  224            // padded CS/BT row width in halves (194 live + pad)

// workspace layout (float indices). OUT aliases MT (MT dead after kF).
// ws+0..15: hdr. ws+64..: pmin[640]. ws+768..: pmax[640].
#define OFF_PMIN 64
#define OFF_PMAX 768
#define OFF_M   32768                          // fp32 MT[el][f][s] (= OUT alias)
#define OFF_CS  (32768 + (size_t)NROW * F_)    // f16 CS[el][f][CSW] hi/lo pairs
#define OFF_BT  (OFF_CS + (size_t)40 * F_ * CSW / 2)   // f16 BT[t][CSW]
#define OFF_PT  (OFF_BT + (size_t)T_ * CSW / 2)        // f16 PT[256][256]

typedef _Float16 half8 __attribute__((ext_vector_type(8)));
typedef float f32x4v __attribute__((ext_vector_type(4)));
typedef float f32x2 __attribute__((ext_vector_type(2)));

__device__ __forceinline__ void put_hl(_Float16* p, float v) {
  _Float16 h = (_Float16)v;
  _Float16 l = (_Float16)(v - (float)h);
  p[0] = h; p[1] = l;
}

// Forced VOP3P packed fp32: d = a*b - c (one v_pk_fma_f32, neg on src2).
__device__ __forceinline__ f32x2 pk_fma_sub(f32x2 a, f32x2 b, f32x2 c) {
  f32x2 d;
  asm("v_pk_fma_f32 %0, %1, %2, %3 neg_lo:[0,0,1] neg_hi:[0,0,1]"
      : "=v"(d) : "v"(a), "v"(b), "v"(c));
  return d;
}
// Forced packed accumulate: a += b (one v_pk_add_f32).
__device__ __forceinline__ void pk_add_acc(f32x2& a, f32x2 b) {
  asm("v_pk_add_f32 %0, %0, %1" : "+v"(a) : "v"(b));
}

// K_pt: PT[c][k] = (f16)P[k][c].
__global__ __launch_bounds__(256) void k_pt(const float* __restrict__ P,
                                            _Float16* __restrict__ PT) {
  const int k = blockIdx.x;
  const int c = threadIdx.x;
  PT[(size_t)c * F_ + k] = (_Float16)P[(size_t)k * F_ + c];
}

// K0: m = matrix @ params via MFMA f16 hi/lo split; writes M TRANSPOSED:
// MT[el][f][s].
// R3 (validated): R1 pipeline (LDS staging + 1-chunk register prefetch) +
// ZERO global atomics — per-block min/max partials, k1 reduces.
__global__ __launch_bounds__(256) void k0_mfma(const float* __restrict__ A,
                                               const _Float16* __restrict__ PT,
                                               float* __restrict__ MT,
                                               float* __restrict__ pmin,
                                               float* __restrict__ pmax) {
  __shared__ __align__(16) _Float16 Ahi[64][40];
  __shared__ __align__(16) _Float16 Alo[64][40];
  __shared__ __align__(16) _Float16 Bl[256][40];
  __shared__ float wmin[4], wmax[4];
  const int tid = threadIdx.x;
  const int wave = tid >> 6, lane = tid & 63;
  const int nn = lane & 15, quad = lane >> 4;
  const int row0 = blockIdx.x * 64;
  const int el = blockIdx.x >> 4;
  const int s0 = (blockIdx.x & 15) * 64;
  const int r = tid >> 2, part = tid & 3;
  const float* asrc = A + (size_t)(row0 + r) * F_ + part * 8;
  const _Float16* bbase = PT + (size_t)tid * F_;
  f32x4v acc[4][4];
#pragma unroll
  for (int rt = 0; rt < 4; ++rt)
#pragma unroll
    for (int ct = 0; ct < 4; ++ct) acc[rt][ct] = (f32x4v){0.f, 0.f, 0.f, 0.f};

  // prefetch chunk 0 into registers
  float4 pa0 = ((const float4*)asrc)[0];
  float4 pa1 = ((const float4*)asrc)[1];
  int4 pb0, pb1, pb2, pb3;
  {
    const int4* bs = (const int4*)bbase;
    pb0 = bs[0]; pb1 = bs[1]; pb2 = bs[2]; pb3 = bs[3];
  }

  for (int kc = 0; kc < 8; ++kc) {
    __syncthreads();   // prior chunk's fragment reads complete; LDS reusable
    {
      float vv[8] = {pa0.x, pa0.y, pa0.z, pa0.w, pa1.x, pa1.y, pa1.z, pa1.w};
      half8 hh, hl;
#pragma unroll
      for (int j = 0; j < 8; ++j) {
        _Float16 h = (_Float16)vv[j];
        hh[j] = h;
        hl[j] = (_Float16)(vv[j] - (float)h);
      }
      *(half8*)&Ahi[r][part * 8] = hh;
      *(half8*)&Alo[r][part * 8] = hl;
      int4* bd = (int4*)&Bl[tid][0];
      bd[0] = pb0; bd[1] = pb1; bd[2] = pb2; bd[3] = pb3;
    }
    if (kc < 7) {
      const float* an = asrc + (kc + 1) * 32;
      pa0 = ((const float4*)an)[0];
      pa1 = ((const float4*)an)[1];
      const int4* bn = (const int4*)(bbase + (kc + 1) * 32);
      pb0 = bn[0]; pb1 = bn[1]; pb2 = bn[2]; pb3 = bn[3];
    }
    __syncthreads();   // LDS tile visible
    half8 afh[4], afl[4], bf[4];
#pragma unroll
    for (int rt = 0; rt < 4; ++rt) {
      afh[rt] = *(const half8*)&Ahi[rt * 16 + nn][quad * 8];
      afl[rt] = *(const half8*)&Alo[rt * 16 + nn][quad * 8];
    }
#pragma unroll
    for (int ct = 0; ct < 4; ++ct)
      bf[ct] = *(const half8*)&Bl[wave * 64 + ct * 16 + nn][quad * 8];
#pragma unroll
    for (int rt = 0; rt < 4; ++rt)
#pragma unroll
      for (int ct = 0; ct < 4; ++ct) {
        acc[rt][ct] = __builtin_amdgcn_mfma_f32_16x16x32_f16(afh[rt], bf[ct], acc[rt][ct], 0, 0, 0);
        acc[rt][ct] = __builtin_amdgcn_mfma_f32_16x16x32_f16(afl[rt], bf[ct], acc[rt][ct], 0, 0, 0);
      }
  }
  float vmin = 3.4e38f, vmax = -3.4e38f;
#pragma unroll
  for (int rt = 0; rt < 4; ++rt)
#pragma unroll
    for (int ct = 0; ct < 4; ++ct) {
      f32x4v c = acc[rt][ct];
      const int col = wave * 64 + ct * 16 + nn;
      const int sl = s0 + rt * 16 + quad * 4;
      *(float4*)&MT[((size_t)el * F_ + col) * S_ + sl] =
          make_float4(c[0], c[1], c[2], c[3]);
      vmin = fminf(vmin, fminf(fminf(c[0], c[1]), fminf(c[2], c[3])));
      vmax = fmaxf(vmax, fmaxf(fmaxf(c[0], c[1]), fmaxf(c[2], c[3])));
    }
#pragma unroll
  for (int off = 32; off; off >>= 1) {
    vmin = fminf(vmin, __shfl_down(vmin, off));
    vmax = fmaxf(vmax, __shfl_down(vmax, off));
  }
  if (lane == 0) { wmin[wave] = vmin; wmax[wave] = vmax; }
  __syncthreads();
  if (tid == 0) {
    pmin[blockIdx.x] = fminf(fminf(wmin[0], wmin[1]), fminf(wmin[2], wmin[3]));
    pmax[blockIdx.x] = fmaxf(fmaxf(wmax[0], wmax[1]), fmaxf(wmax[2], wmax[3]));
  }
}

// K1: final min/max reduction over 640 per-block partials + grid/Fourier
// constants. Single block, 256 threads — replaces all global atomics.
__global__ __launch_bounds__(256) void k1_setup(const float* __restrict__ pmin,
                                                const float* __restrict__ pmax,
                                                float* __restrict__ hdr) {
  __shared__ float sm[4], sx[4];
  const int tid = threadIdx.x;
  float vmin = 3.4e38f, vmax = -3.4e38f;
  for (int i = tid; i < NBLK; i += 256) {
    vmin = fminf(vmin, pmin[i]);
    vmax = fmaxf(vmax, pmax[i]);
  }
#pragma unroll
  for (int off = 32; off; off >>= 1) {
    vmin = fminf(vmin, __shfl_down(vmin, off));
    vmax = fmaxf(vmax, __shfl_down(vmax, off));
  }
  if ((tid & 63) == 0) { sm[tid >> 6] = vmin; sx[tid >> 6] = vmax; }
  __syncthreads();
  if (tid == 0) {
    const float left = fminf(fminf(sm[0], sm[1]), fminf(sm[2], sm[3]));
    const float right = fmaxf(fmaxf(sx[0], sx[1]), fmaxf(sx[2], sx[3]));
    const float dg = (right - left) / 1023.0f;
    const float delta = (right - left) / 1024.0f;
    const float divisor = 0.62665706865775006f;   // sqrt(2*pi)*0.25
    const float scale = delta * 0.5f / divisor;
    const float Pp = (right - left) + 5.0f;       // period (alias gap > 2.4)
    const float sqpi8 = 0.62665706865775006f;     // sqrt(pi/8)
    hdr[0] = left; hdr[1] = dg; hdr[2] = 0.f; hdr[3] = scale;
    hdr[4] = 6.2831853071795864f / Pp;            // omega1
    hdr[5] = 2.0f * sqpi8 / Pp;                   // a_k scale
    hdr[6] = sqpi8 / Pp;                          // a_0
  }
}

// KB: basis matrix BT[t][j], j=2*kidx(+1): kidx 0=DC, 1..48=a_k cos(w_k x_t),
// 49..96=a_k sin. Both hi/lo slots carry the same value (CS carries hi/lo).
__global__ __launch_bounds__(256) void kB(const float* __restrict__ hdr,
                                          _Float16* __restrict__ BT) {
  const int t = blockIdx.x;
  const int j = threadIdx.x;
  if (j >= CSW) return;
  const float left = hdr[0], dg = hdr[1];
  const float w1 = hdr[4], asc = hdr[5], a0 = hdr[6];
  const float x = left + (float)t * dg;
  float v = 0.f;
  const int kidx = j >> 1;
  if (j < 2 * (2 * NH + 1)) {
    if (kidx == 0) v = a0;
    else if (kidx <= NH) {
      float wk = w1 * (float)kidx;
      v = asc * expf(-wk * wk * 0.03125f) * __cosf(wk * x);
    } else {
      float wk = w1 * (float)(kidx - NH);
      v = asc * expf(-wk * wk * 0.03125f) * __sinf(wk * x);
    }
  }
  BT[(size_t)t * CSW + j] = (_Float16)v;
}

// KF: Fourier sums C_k(f)=sum_s cos(w_k m), S_k likewise. Single pass,
// 48 harmonics, Chebyshev 3-term recurrence in FORCED v_pk_fma_f32 /
// v_pk_add_f32 (cos chain in lane.x, sin chain in lane.y) — R4: the
// ext-vector arithmetic was scalarizing (inst-count evidence: ~8.5K
// VALU insts/thread vs ~3.3K packed ideal). One sincos per sample,
// prefetch of next float4, width-32 shuffle reduction. No atomics, no LDS.
__global__ __launch_bounds__(256) void kF(const float* __restrict__ MT,
                                          const float* __restrict__ hdr,
                                          _Float16* __restrict__ CS) {
  const int tid = threadIdx.x;
  const int floc = tid >> 5, slice = tid & 31;
  const int el = blockIdx.x >> 5;
  const int fg = blockIdx.x & 31;
  const int f = fg * 8 + floc;
  const float w1 = hdr[4];
  const float* src = MT + ((size_t)el * F_ + f) * S_ + slice * 32;
  _Float16* csrow = CS + ((size_t)el * F_ + f) * CSW;
  f32x2 acc[NH];
#pragma unroll
  for (int k = 0; k < NH; ++k) acc[k] = (f32x2){0.f, 0.f};
  float4 nxt = ((const float4*)src)[0];
  for (int it = 0; it < 8; ++it) {
    float4 cur = nxt;
    if (it < 7) nxt = ((const float4*)src)[it + 1];   // prefetch next tile
    float mv[4] = {cur.x, cur.y, cur.z, cur.w};
#pragma unroll
    for (int c = 0; c < 4; ++c) {
      float al = w1 * mv[c];
      float s1, c1;
      __sincosf(al, &s1, &c1);
      const float tc = 2.f * c1;
      f32x2 tc2; tc2[0] = tc; tc2[1] = tc;
      f32x2 p;  p[0] = c1;  p[1] = s1;    // current (cos k*a, sin k*a)
      f32x2 pp; pp[0] = 1.f; pp[1] = 0.f; // previous (k-1)
      pk_add_acc(acc[0], p);
#pragma unroll
      for (int k = 1; k < NH; ++k) {
        f32x2 n = pk_fma_sub(tc2, p, pp);  // packed Chebyshev step
        pk_add_acc(acc[k], n);             // packed accumulate
        pp = p; p = n;
      }
    }
  }
#pragma unroll
  for (int off = 16; off; off >>= 1)
#pragma unroll
    for (int k = 0; k < NH; ++k) {
      f32x2 o;
      o[0] = __shfl_down(acc[k][0], off, 32);
      o[1] = __shfl_down(acc[k][1], off, 32);
      pk_add_acc(acc[k], o);
    }
  if (slice == 0) {
    csrow[0] = (_Float16)1024.f;   // DC: C_0 = S count (exact)
    csrow[1] = (_Float16)0.f;
#pragma unroll
    for (int k = 0; k < NH; ++k) {
      put_hl(csrow + 2 * (1 + k), acc[k][0]);        // cos harmonics 1..48
      put_hl(csrow + 2 * (NH + 1 + k), acc[k][1]);   // sin harmonics 1..48
    }
  }
}

// KR: reconstruction GEMM ksum = CS x BT^T via MFMA (7 K-chunks of 32).
// R2: ZERO-LDS / ZERO-BARRIER, direct-fragment-load (16B-aligned rows).
__global__ __launch_bounds__(256) void kR(const _Float16* __restrict__ CS,
                                          const _Float16* __restrict__ BT,
                                          float* __restrict__ OUT) {
  const int tid = threadIdx.x;
  const int wave = tid >> 6, lane = tid & 63;
  const int nn = lane & 15, quad = lane >> 4;
  const int el = blockIdx.x >> 4;
  const int t0 = (blockIdx.x & 15) << 6;

  const _Float16* ab0 = CS + ((size_t)el * F_ + wave * 64 + 0 * 16 + nn) * CSW + quad * 8;
  const _Float16* ab1 = CS + ((size_t)el * F_ + wave * 64 + 1 * 16 + nn) * CSW + quad * 8;
  const _Float16* ab2 = CS + ((size_t)el * F_ + wave * 64 + 2 * 16 + nn) * CSW + quad * 8;
  const _Float16* ab3 = CS + ((size_t)el * F_ + wave * 64 + 3 * 16 + nn) * CSW + quad * 8;
  const _Float16* bb0 = BT + (size_t)(t0 + 0 * 16 + nn) * CSW + quad * 8;
  const _Float16* bb1 = BT + (size_t)(t0 + 1 * 16 + nn) * CSW + quad * 8;
  const _Float16* bb2 = BT + (size_t)(t0 + 2 * 16 + nn) * CSW + quad * 8;
  const _Float16* bb3 = BT + (size_t)(t0 + 3 * 16 + nn) * CSW + quad * 8;

  f32x4v acc[4][4];
#pragma unroll
  for (int ft = 0; ft < 4; ++ft)
#pragma unroll
    for (int tn = 0; tn < 4; ++tn) acc[ft][tn] = (f32x4v){0.f, 0.f, 0.f, 0.f};

  half8 pa[4], pb[4];
  pa[0] = *(const half8*)ab0; pa[1] = *(const half8*)ab1;
  pa[2] = *(const half8*)ab2; pa[3] = *(const half8*)ab3;
  pb[0] = *(const half8*)bb0; pb[1] = *(const half8*)bb1;
  pb[2] = *(const half8*)bb2; pb[3] = *(const half8*)bb3;

#pragma unroll
  for (int kc = 0; kc < CSW / 32; ++kc) {
    half8 af[4], bf[4];
#pragma unroll
    for (int ft = 0; ft < 4; ++ft) af[ft] = pa[ft];
#pragma unroll
    for (int tn = 0; tn < 4; ++tn) bf[tn] = pb[tn];
    if (kc < CSW / 32 - 1) {
      const int o = (kc + 1) * 32;
      pa[0] = *(const half8*)(ab0 + o); pa[1] = *(const half8*)(ab1 + o);
      pa[2] = *(const half8*)(ab2 + o); pa[3] = *(const half8*)(ab3 + o);
      pb[0] = *(const half8*)(bb0 + o); pb[1] = *(const half8*)(bb1 + o);
      pb[2] = *(const half8*)(bb2 + o); pb[3] = *(const half8*)(bb3 + o);
    }
#pragma unroll
    for (int ft = 0; ft < 4; ++ft)
#pragma unroll
      for (int tn = 0; tn < 4; ++tn)
        acc[ft][tn] = __builtin_amdgcn_mfma_f32_16x16x32_f16(af[ft], bf[tn], acc[ft][tn], 0, 0, 0);
  }

  float* Ob = OUT + (size_t)el * F_ * T_ + t0;
#pragma unroll
  for (int ft = 0; ft < 4; ++ft)
#pragma unroll
    for (int tn = 0; tn < 4; ++tn) {
      f32x4v c = acc[ft][tn];
      const int fb = wave * 64 + ft * 16 + quad * 4;
      const int tc = tn * 16 + nn;
      Ob[(size_t)(fb + 0) * T_ + tc] = c[0];
      Ob[(size_t)(fb + 1) * T_ + tc] = c[1];
      Ob[(size_t)(fb + 2) * T_ + tc] = c[2];
      Ob[(size_t)(fb + 3) * T_ + tc] = c[3];
    }
}

// K4: epilogue (unchanged, validated).
__global__ __launch_bounds__(256) void k4_epi(const float* __restrict__ OUT,
                                              const float* __restrict__ hdr,
                                              const float* __restrict__ dl,
                                              float* __restrict__ out) {
  __shared__ float rs[4][6];
  const int tid = threadIdx.x;
  const int l = blockIdx.x >> 8;
  const int f = blockIdx.x & 255;
  const float left = hdr[0], dg = hdr[1], scale = hdr[3];
  const int t = 4 * tid;
  float etv[4];
#pragma unroll
  for (int d = 0; d < 4; ++d) {
    float x = left + (float)(t + d) * dg;
    etv[d] = expf(-8.0f * x * x);
  }
  float red[E_][4];
#pragma unroll
  for (int e = 0; e < E_; ++e) {
    float4 ks = *(const float4*)(OUT + (((size_t)(e * L_ + l)) * F_ + f) * T_ + t);
    const float dlv = dl[e * L_ + l];
    const float zc = (float)S_ - dlv;
    const float idl = 1.0f / dlv;
    red[e][0] = (ks.x - zc * etv[0]) * idl;
    red[e][1] = (ks.y - zc * etv[1]) * idl;
    red[e][2] = (ks.z - zc * etv[2]) * idl;
    red[e][3] = (ks.w - zc * etv[3]) * idl;
  }
  float D[6];
  const int pa[6] = {0, 0, 0, 1, 1, 2};
  const int pb[6] = {1, 2, 3, 2, 3, 3};
#pragma unroll
  for (int p = 0; p < 6; ++p) {
    float s = 0.f;
#pragma unroll
    for (int d = 0; d < 4; ++d) s += fabsf(red[pa[p]][d] - red[pb[p]][d]);
    D[p] = s;
  }
#pragma unroll
  for (int off = 32; off; off >>= 1)
#pragma unroll
    for (int p = 0; p < 6; ++p) D[p] += __shfl_down(D[p], off);
  if ((tid & 63) == 0) {
#pragma unroll
    for (int p = 0; p < 6; ++p) rs[tid >> 6][p] = D[p];
  }
  __syncthreads();
  if (tid == 0) {
    float Tp[6];
#pragma unroll
    for (int p = 0; p < 6; ++p)
      Tp[p] = (rs[0][p] + rs[1][p] + rs[2][p] + rs[3][p]) * scale;
    float test = Tp[0];
#pragma unroll
    for (int p = 1; p < 6; ++p) test = fmaxf(test, Tp[p]);
    float train = fmaxf(fmaxf(Tp[1], Tp[2]), Tp[5]);
    out[l * F_ + f] = train;
    out[L_ * F_ + l * F_ + f] = test;
  }
}

extern "C" void kernel_launch(void* const* d_in, const int* in_sizes, int n_in,
                              void* d_out, int out_size, void* d_ws, size_t ws_size,
                              hipStream_t stream) {
  const float* A  = (const float*)d_in[0];   // matrix (4,10,1024,256)
  const float* dl = (const float*)d_in[1];   // data_len (4,10)
  const float* P  = (const float*)d_in[2];   // params (256,256)
  float* out = (float*)d_out;
  float* ws = (float*)d_ws;
  float* hdr = ws;
  float* pmin = ws + OFF_PMIN;               // 640 per-block minima
  float* pmax = ws + OFF_PMAX;               // 640 per-block maxima
  float* MT  = ws + OFF_M;                   // fp32 GEMM result (dead after kF)
  float* OUT = ws + OFF_M;                   // OUT aliases MT
  _Float16* CS = (_Float16*)(ws + OFF_CS);
  _Float16* BT = (_Float16*)(ws + OFF_BT);
  _Float16* PT = (_Float16*)(ws + OFF_PT);

  // Determinism under 0xAA ws-poison: zero all f16 regions (pads included).
  // pmin/pmax need no clearing: every element written by k0 before k1 reads.
  (void)hipMemsetAsync(CS, 0, (size_t)40 * F_ * CSW * 2, stream);   // 4.6 MB
  (void)hipMemsetAsync(BT, 0, (size_t)T_ * CSW * 2, stream);
  (void)hipMemsetAsync(PT, 0, (size_t)F_ * F_ * 2, stream);

  k_pt<<<F_, 256, 0, stream>>>(P, PT);
  k0_mfma<<<NBLK, 256, 0, stream>>>(A, PT, MT, pmin, pmax);
  k1_setup<<<1, 256, 0, stream>>>(pmin, pmax, hdr);
  kB<<<T_, 256, 0, stream>>>(hdr, BT);
  kF<<<(E_ * L_) * 32, 256, 0, stream>>>(MT, hdr, CS);
  kR<<<(E_ * L_) * 16, 256, 0, stream>>>(CS, BT, OUT);
  k4_epi<<<L_ * F_, 256, 0, stream>>>(OUT, hdr, dl, out);
}